// Round 13
// baseline (268.663 us; speedup 1.0000x reference)
//
#include <hip/hip_runtime.h>

// MHA forward: S=2048, B=4, E=512, H=8, D=64.
// qkv_kernel -> maskprep_kernel -> attn_kernel -> oproj_kernel.
// R13 = R12 (PASS baseline) + k-split attn re-landed WITH exp2f arithmetic
// (R10's failure is now attributed to inline-asm v_exp_f32, not the split):
// 8 waves/block (512 thr); waves 0-3 take k 0..1023, waves 4-7 take
// k 1024..2047 on the same 128 q-rows. Fixed-reference softmax makes the
// merge an add: each wave swaps its other d-half O-partial + lsum with
// partner (wave^4) via barrier-protected LDS reuse. 16 waves/CU = 4/SIMD.

#define L2E 1.44269504088896340736f

typedef __attribute__((ext_vector_type(8))) __bf16 bf16x8;
typedef __attribute__((ext_vector_type(4))) float f32x4;
typedef __attribute__((ext_vector_type(16))) float f32x16;

// packed bf16 pair via native casts (compiler emits v_cvt_pk_bf16_f32)
static __device__ __forceinline__ unsigned pk2(float a, float b) {
    union { unsigned u; __bf16 h[2]; } cv;
    cv.h[0] = (__bf16)a; cv.h[1] = (__bf16)b;
    return cv.u;
}

static __device__ __forceinline__ unsigned short f2bf(float f) {
    union { unsigned short s; __bf16 h; } cv;
    cv.h = (__bf16)f;
    return cv.s;
}

static __device__ __forceinline__ float bflo(unsigned u) {
    union { unsigned u; float f; } cv; cv.u = u << 16; return cv.f;
}
static __device__ __forceinline__ float bfhi(unsigned u) {
    union { unsigned u; float f; } cv; cv.u = u & 0xFFFF0000u; return cv.f;
}

// ---------------------------------------------------------------------------
// Kernel 0: QKV projection. z selects (input, weight slice, dst).
//   z=0 -> Qp[bh][s][d] scaled by L2E/8, z=1 -> Kp, z=2 -> Vt[bh][d][s].
// ---------------------------------------------------------------------------
__global__ __launch_bounds__(256) void qkv_kernel(
    const float* __restrict__ Xq, const float* __restrict__ Xk,
    const float* __restrict__ Xv, const float* __restrict__ W,
    const float* __restrict__ bias,
    unsigned short* __restrict__ Qp, unsigned short* __restrict__ Kp,
    unsigned short* __restrict__ Vt)
{
    __shared__ unsigned short lA[128][40];
    __shared__ unsigned short lB[128][40];

    const int z = blockIdx.z;
    const float* X  = (z == 0) ? Xq : (z == 1) ? Xk : Xv;
    const float* Wz = W + (size_t)z * 512 * 512;
    const int rb = blockIdx.y * 128;
    const int nb = blockIdx.x * 128;
    const int tid  = threadIdx.x;
    const int lane = tid & 63, wave = tid >> 6;
    const int wr = wave >> 1, wc = wave & 1;
    const int lq = lane & 15, lg = lane >> 4;

    f32x4 acc[4][4];
#pragma unroll
    for (int i = 0; i < 4; ++i)
#pragma unroll
        for (int j = 0; j < 4; ++j) acc[i][j] = (f32x4){0.f, 0.f, 0.f, 0.f};

    const int srow = tid >> 1;
    const int scol = (tid & 1) * 16;

    for (int kt = 0; kt < 16; ++kt) {
        const int k0 = kt * 32;
        if (kt) __syncthreads();
        {
            const float* g = X + (size_t)(rb + srow) * 512 + k0 + scol;
            float4 x0 = *(const float4*)(g + 0);
            float4 x1 = *(const float4*)(g + 4);
            float4 x2 = *(const float4*)(g + 8);
            float4 x3 = *(const float4*)(g + 12);
            uint4 w0, w1;
            w0.x = pk2(x0.x, x0.y); w0.y = pk2(x0.z, x0.w);
            w0.z = pk2(x1.x, x1.y); w0.w = pk2(x1.z, x1.w);
            w1.x = pk2(x2.x, x2.y); w1.y = pk2(x2.z, x2.w);
            w1.z = pk2(x3.x, x3.y); w1.w = pk2(x3.z, x3.w);
            *(uint4*)&lA[srow][scol] = w0;
            *(uint4*)&lA[srow][scol + 8] = w1;
        }
        {
            const float* g = Wz + (size_t)(nb + srow) * 512 + k0 + scol;
            float4 x0 = *(const float4*)(g + 0);
            float4 x1 = *(const float4*)(g + 4);
            float4 x2 = *(const float4*)(g + 8);
            float4 x3 = *(const float4*)(g + 12);
            uint4 w0, w1;
            w0.x = pk2(x0.x, x0.y); w0.y = pk2(x0.z, x0.w);
            w0.z = pk2(x1.x, x1.y); w0.w = pk2(x1.z, x1.w);
            w1.x = pk2(x2.x, x2.y); w1.y = pk2(x2.z, x2.w);
            w1.z = pk2(x3.x, x3.y); w1.w = pk2(x3.z, x3.w);
            *(uint4*)&lB[srow][scol] = w0;
            *(uint4*)&lB[srow][scol + 8] = w1;
        }
        __syncthreads();

        bf16x8 af[4], bf[4];
#pragma unroll
        for (int mi = 0; mi < 4; ++mi)
            af[mi] = *(const bf16x8*)&lA[wr * 64 + mi * 16 + lq][lg * 8];
#pragma unroll
        for (int ni = 0; ni < 4; ++ni)
            bf[ni] = *(const bf16x8*)&lB[wc * 64 + ni * 16 + lq][lg * 8];
#pragma unroll
        for (int mi = 0; mi < 4; ++mi)
#pragma unroll
            for (int ni = 0; ni < 4; ++ni)
                acc[mi][ni] = __builtin_amdgcn_mfma_f32_16x16x32_bf16(
                    af[mi], bf[ni], acc[mi][ni], 0, 0, 0);
    }

    const float* bz = bias + z * 512;
#pragma unroll
    for (int ni = 0; ni < 4; ++ni) {
        const int n = nb + wc * 64 + ni * 16 + lq;
        const float bv = bz[n];
        const int h = n >> 6, d = n & 63;
#pragma unroll
        for (int mi = 0; mi < 4; ++mi) {
#pragma unroll
            for (int r = 0; r < 4; ++r) {
                const int t = rb + wr * 64 + mi * 16 + lg * 4 + r;
                float v = acc[mi][ni][r] + bv;
                const int s = t >> 2, b = t & 3;
                if (z == 0) {
                    v *= 0.125f * L2E;
                    Qp[((size_t)(b * 8 + h) * 2048 + s) * 64 + d] = f2bf(v);
                } else if (z == 1) {
                    Kp[((size_t)(b * 8 + h) * 2048 + s) * 64 + d] = f2bf(v);
                } else {
                    Vt[((size_t)(b * 8 + h) * 64 + d) * 2048 + s] = f2bf(v);
                }
            }
        }
    }
}

// ---------------------------------------------------------------------------
// Kernel 0.5: mask -> bf16 fragment layout via LDS transpose (coalesced).
// grid (8 k-chunks of 256, 256 bq); 256 threads.  (verified R12)
// Mf[(bq*64+kt)*1024 + lane*16 + jj] =
//   mask[b][qt*32+(lane&31)][kt*32 + (jj&3)+8*(jj>>2)+4*(lane>>5)] * L2E
// ---------------------------------------------------------------------------
__global__ __launch_bounds__(256) void maskprep_kernel(
    const float* __restrict__ mask, unsigned short* __restrict__ Mf)
{
    __shared__ float lT[32][261];
    const int tid = threadIdx.x;
    const int bq = blockIdx.y;                  // b*64 + qt
    const int kx = blockIdx.x;                  // k-chunk of 256
    const float* base = mask + ((size_t)(bq >> 6) * 2048 + (bq & 63) * 32) * 2048
                        + (size_t)kx * 256;

    const int r = tid >> 3, ci = tid & 7;
    const float* rp = base + (size_t)r * 2048;
#pragma unroll
    for (int j = 0; j < 8; ++j) {
        const int c = (ci + j * 8) * 4;
        float4 v = *(const float4*)(rp + c);
        lT[r][c + 0] = v.x * L2E;
        lT[r][c + 1] = v.y * L2E;
        lT[r][c + 2] = v.z * L2E;
        lT[r][c + 3] = v.w * L2E;
    }
    __syncthreads();

    const int w = tid >> 6, lane = tid & 63;
    const int lc = lane & 31, hi = lane >> 5;
#pragma unroll
    for (int t = 0; t < 2; ++t) {
        const int ktl = w * 2 + t;
        float p[16];
#pragma unroll
        for (int jj = 0; jj < 16; ++jj)
            p[jj] = lT[lc][ktl * 32 + (jj & 3) + 8 * (jj >> 2) + 4 * hi];
        unsigned short* dst = Mf + ((size_t)bq * 64 + kx * 8 + ktl) * 1024 + lane * 16;
        *(uint4*)(dst) = make_uint4(pk2(p[0], p[1]), pk2(p[2], p[3]),
                                    pk2(p[4], p[5]), pk2(p[6], p[7]));
        *(uint4*)(dst + 8) = make_uint4(pk2(p[8], p[9]),  pk2(p[10], p[11]),
                                        pk2(p[12], p[13]), pk2(p[14], p[15]));
    }
}

// ---------------------------------------------------------------------------
// Kernel 1: flash attention, 32x32x16 MFMA, swapped QK^T, k-split 8 waves.
// grid (16 q-tiles of 128, 32 bh), 512 threads.
// wave w: qw = w&3 (q-subtile of 32 rows), kg = w>>2 (k-half).
// Per-group dbuf K/V LDS (XOR swizzle), 1 barrier/tile, reg prefetch.
// COMPUTE arithmetic identical to R12 (exp2f + native pk2).
// ---------------------------------------------------------------------------
#define SWAP32(a, b) asm("v_permlane32_swap_b32 %0, %1" : "+v"(a), "+v"(b))

#define COMPUTE(KC, VC, M) do {                                                \
    bf16x8 pf[4];                                                              \
    _Pragma("unroll")                                                          \
    for (int kblk = 0; kblk < 2; ++kblk) {                                     \
        f32x16 z;                                                              \
        {                                                                      \
            const uint4 m0 = M[kblk][0], m1 = M[kblk][1];                      \
            z[0]  = bflo(m0.x); z[1]  = bfhi(m0.x);                            \
            z[2]  = bflo(m0.y); z[3]  = bfhi(m0.y);                            \
            z[4]  = bflo(m0.z); z[5]  = bfhi(m0.z);                            \
            z[6]  = bflo(m0.w); z[7]  = bfhi(m0.w);                            \
            z[8]  = bflo(m1.x); z[9]  = bfhi(m1.x);                            \
            z[10] = bflo(m1.y); z[11] = bfhi(m1.y);                            \
            z[12] = bflo(m1.z); z[13] = bfhi(m1.z);                            \
            z[14] = bflo(m1.w); z[15] = bfhi(m1.w);                            \
        }                                                                      \
        __builtin_amdgcn_s_setprio(1);                                         \
        _Pragma("unroll")                                                      \
        for (int s = 0; s < 4; ++s) {                                          \
            bf16x8 kf = *(const bf16x8*)((KC) + fof[kblk][s]);                 \
            z = __builtin_amdgcn_mfma_f32_32x32x16_bf16(kf, qf[s], z, 0,0,0);  \
        }                                                                      \
        __builtin_amdgcn_s_setprio(0);                                         \
        float p[16];                                                           \
        _Pragma("unroll")                                                      \
        for (int i = 0; i < 16; ++i) p[i] = exp2f(z[i]);                       \
        lsum += (((p[0]+p[1])+(p[2]+p[3])) + ((p[4]+p[5])+(p[6]+p[7])))        \
              + (((p[8]+p[9])+(p[10]+p[11])) + ((p[12]+p[13])+(p[14]+p[15]))); \
        unsigned a0 = pk2(p[0], p[1]),   b0 = pk2(p[4], p[5]);                 \
        unsigned a1 = pk2(p[2], p[3]),   b1 = pk2(p[6], p[7]);                 \
        SWAP32(a0, b0); SWAP32(a1, b1);                                        \
        union { unsigned w[4]; bf16x8 v; } u0;                                 \
        u0.w[0] = a0; u0.w[1] = a1; u0.w[2] = b0; u0.w[3] = b1;                \
        pf[kblk*2] = u0.v;                                                     \
        unsigned c0 = pk2(p[8], p[9]),   d0 = pk2(p[12], p[13]);               \
        unsigned c1 = pk2(p[10], p[11]), d1 = pk2(p[14], p[15]);               \
        SWAP32(c0, d0); SWAP32(c1, d1);                                        \
        union { unsigned w[4]; bf16x8 v; } u1;                                 \
        u1.w[0] = c0; u1.w[1] = c1; u1.w[2] = d0; u1.w[3] = d1;                \
        pf[kblk*2+1] = u1.v;                                                   \
    }                                                                          \
    __builtin_amdgcn_s_setprio(1);                                             \
    _Pragma("unroll")                                                          \
    for (int s = 0; s < 4; ++s) {                                              \
        bf16x8 vf0 = *(const bf16x8*)((VC) + fof[0][s]);                       \
        o0 = __builtin_amdgcn_mfma_f32_32x32x16_bf16(vf0, pf[s], o0, 0,0,0);   \
        bf16x8 vf1 = *(const bf16x8*)((VC) + fof[1][s]);                       \
        o1 = __builtin_amdgcn_mfma_f32_32x32x16_bf16(vf1, pf[s], o1, 0,0,0);   \
    }                                                                          \
    __builtin_amdgcn_s_setprio(0);                                             \
} while (0)

#define LOADNEXT(MD) do {                                                      \
    ka = *(const uint4*)(pgK); kc = *(const uint4*)(pgK + 8);                  \
    va = *(const uint4*)(pgV); vc = *(const uint4*)(pgV + 8);                  \
    MD[0][0] = *(const uint4*)(pmf);                                           \
    MD[0][1] = *(const uint4*)(pmf + 8);                                       \
    MD[1][0] = *(const uint4*)(pmf + 1024);                                    \
    MD[1][1] = *(const uint4*)(pmf + 1032);                                    \
    pgK += 4096; pgV += 64; pmf += 2048;                                       \
} while (0)

#define STORE(BUF) do {                                                        \
    *(uint4*)&lK[kg][BUF][srow][su0 * 8] = ka;                                 \
    *(uint4*)&lK[kg][BUF][srow][su1 * 8] = kc;                                 \
    *(uint4*)&lV[kg][BUF][srow][su0 * 8] = va;                                 \
    *(uint4*)&lV[kg][BUF][srow][su1 * 8] = vc;                                 \
} while (0)

__global__ __launch_bounds__(512, 4) void attn_kernel(
    const unsigned short* __restrict__ Qp, const unsigned short* __restrict__ Kp,
    const unsigned short* __restrict__ Vt, const unsigned short* __restrict__ Mf,
    unsigned short* __restrict__ AO)
{
    __shared__ __align__(16) char smem[65536];
    unsigned short (*lK)[2][64][64] = (unsigned short (*)[2][64][64])(smem);
    unsigned short (*lV)[2][64][64] = (unsigned short (*)[2][64][64])(smem + 32768);
    float* ex = (float*)smem;   // reused after compute for the O exchange

    const int bh = blockIdx.y;
    const int b = bh >> 3, h = bh & 7;
    const int qb = blockIdx.x * 128;
    const int tid  = threadIdx.x;
    const int lane = tid & 63, wave = tid >> 6;
    const int qw = wave & 3, kg = wave >> 2;
    const int lc = lane & 31, hi = lane >> 5;
    const int qg = qb + qw * 32 + lc;

    // Q B-fragments: lane needs Q[qg][s*16 + hi*8 + 0..7]
    bf16x8 qf[4];
    {
        const unsigned short* qp = Qp + ((size_t)bh * 2048 + qg) * 64 + hi * 8;
#pragma unroll
        for (int s = 0; s < 4; ++s)
            qf[s] = *(const bf16x8*)(qp + s * 16);
    }

    f32x16 o0, o1;
#pragma unroll
    for (int i = 0; i < 16; ++i) { o0[i] = 0.f; o1[i] = 0.f; }
    float lsum = 0.f;

    // K/V fragment byte-offsets in one group's [64][64]-short tile:
    // row = blk*32 + lc; 16B-unit = (2s|hi) ^ (row&7)
    int fof[2][4];
#pragma unroll
    for (int blk = 0; blk < 2; ++blk)
#pragma unroll
        for (int s = 0; s < 4; ++s)
            fof[blk][s] = (blk * 32 + lc) * 128 +
                          ((((s << 1) | hi) ^ (lane & 7)) * 16);

    const char* lK0c = (const char*)&lK[kg][0][0][0];
    const char* lK1c = (const char*)&lK[kg][1][0][0];
    const char* lV0c = (const char*)&lV[kg][0][0][0];
    const char* lV1c = (const char*)&lV[kg][1][0][0];

    // staging: each group's 256 threads stage that group's K/V tile pair
    const int gtid = tid & 255;
    const int srow = gtid >> 2;
    const int scu  = (gtid & 3) * 2;
    const int su0  = (scu    ) ^ (srow & 7);
    const int su1  = (scu + 1) ^ (srow & 7);
    const unsigned short* pgK = Kp + (size_t)bh * 2048 * 64
                                + (size_t)(kg * 1024 + srow) * 64 + scu * 8;
    const unsigned short* pgV = Vt + (size_t)bh * 64 * 2048
                                + (size_t)srow * 2048 + kg * 1024 + scu * 8;
    // group kg covers kt tiles [kg*32, kg*32+31] (1024 k / 32 per kt tile)
    const unsigned short* pmf = Mf +
        ((size_t)(b * 64 + (qb >> 5) + qw) * 64 + kg * 32) * 1024 + lane * 16;

    uint4 ka, kc, va, vc;
    uint4 mA[2][2], mB[2][2];

    LOADNEXT(mA);
    STORE(0);
    __syncthreads();

    for (int kb2 = 0; kb2 < 8; ++kb2) {
        {
            LOADNEXT(mB);
            COMPUTE(lK0c, lV0c, mA);
            STORE(1);
            __syncthreads();
        }
        {
            if (kb2 < 7) LOADNEXT(mA);
            COMPUTE(lK1c, lV1c, mB);
            if (kb2 < 7) {
                STORE(0);
                __syncthreads();
            }
        }
    }
    __syncthreads();    // all waves done with K/V LDS; safe to reuse as ex

    // within-wave: halves (lane, lane^32) hold disjoint k partials
    lsum += __shfl_xor(lsum, 32);

    // cross-group exchange: wave writes its OTHER d-half + lsum, stride 18 f32
    {
        float* slot = ex + ((size_t)wave * 64 + lane) * 18;
        if (kg == 0) {
#pragma unroll
            for (int i = 0; i < 8; ++i)
                *(float2*)(slot + 2 * i) = make_float2(o1[2*i], o1[2*i+1]);
        } else {
#pragma unroll
            for (int i = 0; i < 8; ++i)
                *(float2*)(slot + 2 * i) = make_float2(o0[2*i], o0[2*i+1]);
        }
        slot[16] = lsum;
    }
    __syncthreads();

    const float* pslot = ex + ((size_t)(wave ^ 4) * 64 + lane) * 18;
    const float lt = lsum + pslot[16];
    const float inv = 1.0f / lt;

    unsigned short* ao = AO + ((size_t)qg * 4 + b) * 512 + h * 64;
    if (kg == 0) {
#pragma unroll
        for (int g = 0; g < 4; ++g) {
            const int d0 = g * 8 + hi * 4;
            float s0 = (o0[4*g+0] + pslot[4*g+0]) * inv;
            float s1 = (o0[4*g+1] + pslot[4*g+1]) * inv;
            float s2 = (o0[4*g+2] + pslot[4*g+2]) * inv;
            float s3 = (o0[4*g+3] + pslot[4*g+3]) * inv;
            *(uint2*)(ao + d0) = make_uint2(pk2(s0, s1), pk2(s2, s3));
        }
    } else {
#pragma unroll
        for (int g = 0; g < 4; ++g) {
            const int d0 = g * 8 + hi * 4;
            float s0 = (o1[4*g+0] + pslot[4*g+0]) * inv;
            float s1 = (o1[4*g+1] + pslot[4*g+1]) * inv;
            float s2 = (o1[4*g+2] + pslot[4*g+2]) * inv;
            float s3 = (o1[4*g+3] + pslot[4*g+3]) * inv;
            *(uint2*)(ao + 32 + d0) = make_uint2(pk2(s0, s1), pk2(s2, s3));
        }
    }
}

// ---------------------------------------------------------------------------
// Kernel 2: output projection. out = AO(bf16) @ W_out^T + b_out (fp32 out).
// ---------------------------------------------------------------------------
__global__ __launch_bounds__(256) void oproj_kernel(
    const unsigned short* __restrict__ A, const float* __restrict__ W,
    const float* __restrict__ bias, float* __restrict__ out)
{
    __shared__ unsigned short lA[128][40];
    __shared__ unsigned short lB[128][40];

    const int rb = blockIdx.y * 128;
    const int nb = blockIdx.x * 128;
    const int tid  = threadIdx.x;
    const int lane = tid & 63, wave = tid >> 6;
    const int wr = wave >> 1, wc = wave & 1;
    const int lq = lane & 15, lg = lane >> 4;

    f32x4 acc[4][4];
#pragma unroll
    for (int i = 0; i < 4; ++i)
#pragma unroll
        for (int j = 0; j < 4; ++j) acc[i][j] = (f32x4){0.f, 0.f, 0.f, 0.f};

    const int srow = tid >> 1;
    const int scol = (tid & 1) * 16;

    for (int kt = 0; kt < 16; ++kt) {
        const int k0 = kt * 32;
        if (kt) __syncthreads();
        {
            const unsigned short* g = A + (size_t)(rb + srow) * 512 + k0 + scol;
            *(uint4*)&lA[srow][scol]     = *(const uint4*)g;
            *(uint4*)&lA[srow][scol + 8] = *(const uint4*)(g + 8);
        }
        {
            const float* g = W + (size_t)(nb + srow) * 512 + k0 + scol;
            float4 x0 = *(const float4*)(g + 0);
            float4 x1 = *(const float4*)(g + 4);
            float4 x2 = *(const float4*)(g + 8);
            float4 x3 = *(const float4*)(g + 12);
            uint4 w0, w1;
            w0.x = pk2(x0.x, x0.y); w0.y = pk2(x0.z, x0.w);
            w0.z = pk2(x1.x, x1.y); w0.w = pk2(x1.z, x1.w);
            w1.x = pk2(x2.x, x2.y); w1.y = pk2(x2.z, x2.w);
            w1.z = pk2(x3.x, x3.y); w1.w = pk2(x3.z, x3.w);
            *(uint4*)&lB[srow][scol] = w0;
            *(uint4*)&lB[srow][scol + 8] = w1;
        }
        __syncthreads();

        bf16x8 af[4], bfr[4];
#pragma unroll
        for (int mi = 0; mi < 4; ++mi)
            af[mi] = *(const bf16x8*)&lA[wr * 64 + mi * 16 + lq][lg * 8];
#pragma unroll
        for (int ni = 0; ni < 4; ++ni)
            bfr[ni] = *(const bf16x8*)&lB[wc * 64 + ni * 16 + lq][lg * 8];
#pragma unroll
        for (int mi = 0; mi < 4; ++mi)
#pragma unroll
            for (int ni = 0; ni < 4; ++ni)
                acc[mi][ni] = __builtin_amdgcn_mfma_f32_16x16x32_bf16(
                    af[mi], bfr[ni], acc[mi][ni], 0, 0, 0);
    }

#pragma unroll
    for (int ni = 0; ni < 4; ++ni) {
        const int n = nb + wc * 64 + ni * 16 + lq;
        const float bv = bias[n];
#pragma unroll
        for (int mi = 0; mi < 4; ++mi) {
#pragma unroll
            for (int r = 0; r < 4; ++r) {
                const int t = rb + wr * 64 + mi * 16 + lg * 4 + r;
                out[(size_t)t * 512 + n] = acc[mi][ni][r] + bv;
            }
        }
    }
}

extern "C" void kernel_launch(void* const* d_in, const int* in_sizes, int n_in,
                              void* d_out, int out_size, void* d_ws, size_t ws_size,
                              hipStream_t stream)
{
    (void)in_sizes; (void)n_in; (void)out_size; (void)ws_size;
    const float* query = (const float*)d_in[0];
    const float* key   = (const float*)d_in[1];
    const float* value = (const float*)d_in[2];
    const float* mask  = (const float*)d_in[3];
    const float* w_in  = (const float*)d_in[4];
    const float* b_in  = (const float*)d_in[5];
    const float* w_out = (const float*)d_in[6];
    const float* b_out = (const float*)d_in[7];
    float* out = (float*)d_out;

    char* ws = (char*)d_ws;
    unsigned short* Qp = (unsigned short*)(ws);                            // [32][2048][64]
    unsigned short* Kp = (unsigned short*)(ws + (size_t)8 * 1024 * 1024);  // [32][2048][64]
    unsigned short* Vt = (unsigned short*)(ws + (size_t)16 * 1024 * 1024); // [32][64][2048]
    unsigned short* AO = (unsigned short*)(ws + (size_t)24 * 1024 * 1024); // [8192][512]
    unsigned short* Mf = (unsigned short*)(ws + (size_t)32 * 1024 * 1024); // [4][64][64][64][16]

    qkv_kernel<<<dim3(4, 64, 3), 256, 0, stream>>>(query, key, value, w_in, b_in,
                                                   Qp, Kp, Vt);
    maskprep_kernel<<<dim3(8, 256), 256, 0, stream>>>(mask, Mf);
    attn_kernel<<<dim3(16, 32), 512, 0, stream>>>(Qp, Kp, Vt, Mf, AO);
    oproj_kernel<<<dim3(4, 64), 256, 0, stream>>>(AO, w_out, b_out, out);
}

// Round 14
// 159.250 us; speedup vs baseline: 1.6870x; 1.6870x over previous
//
#include <hip/hip_runtime.h>

// MHA forward: S=2048, B=4, E=512, H=8, D=64.
// qkv_kernel -> maskprep_kernel -> attn_kernel -> oproj_kernel.
// R14 = R13 with the register-spill fixed: __launch_bounds__(512, 4) had
// forced a 64-VGPR allocation target -> o0/o1 accumulators spilled to
// scratch (WRITE_SIZE 412 MB, attn 190us). (512, 2) caps at 256 VGPR;
// actual need ~120 -> no spill, and 64KB LDS/block already gives
// 2 blocks/CU = 16 waves/CU = 4 waves/SIMD.
// k-split attn (verified correct in R13): 8 waves/block, waves 0-3 take
// k 0..1023, waves 4-7 take k 1024..2047 on the same 128 q-rows;
// fixed-reference softmax -> merge is an add via LDS exchange.

#define L2E 1.44269504088896340736f

typedef __attribute__((ext_vector_type(8))) __bf16 bf16x8;
typedef __attribute__((ext_vector_type(4))) float f32x4;
typedef __attribute__((ext_vector_type(16))) float f32x16;

// packed bf16 pair via native casts (compiler emits v_cvt_pk_bf16_f32)
static __device__ __forceinline__ unsigned pk2(float a, float b) {
    union { unsigned u; __bf16 h[2]; } cv;
    cv.h[0] = (__bf16)a; cv.h[1] = (__bf16)b;
    return cv.u;
}

static __device__ __forceinline__ unsigned short f2bf(float f) {
    union { unsigned short s; __bf16 h; } cv;
    cv.h = (__bf16)f;
    return cv.s;
}

static __device__ __forceinline__ float bflo(unsigned u) {
    union { unsigned u; float f; } cv; cv.u = u << 16; return cv.f;
}
static __device__ __forceinline__ float bfhi(unsigned u) {
    union { unsigned u; float f; } cv; cv.u = u & 0xFFFF0000u; return cv.f;
}

// ---------------------------------------------------------------------------
// Kernel 0: QKV projection. z selects (input, weight slice, dst).
//   z=0 -> Qp[bh][s][d] scaled by L2E/8, z=1 -> Kp, z=2 -> Vt[bh][d][s].
// ---------------------------------------------------------------------------
__global__ __launch_bounds__(256) void qkv_kernel(
    const float* __restrict__ Xq, const float* __restrict__ Xk,
    const float* __restrict__ Xv, const float* __restrict__ W,
    const float* __restrict__ bias,
    unsigned short* __restrict__ Qp, unsigned short* __restrict__ Kp,
    unsigned short* __restrict__ Vt)
{
    __shared__ unsigned short lA[128][40];
    __shared__ unsigned short lB[128][40];

    const int z = blockIdx.z;
    const float* X  = (z == 0) ? Xq : (z == 1) ? Xk : Xv;
    const float* Wz = W + (size_t)z * 512 * 512;
    const int rb = blockIdx.y * 128;
    const int nb = blockIdx.x * 128;
    const int tid  = threadIdx.x;
    const int lane = tid & 63, wave = tid >> 6;
    const int wr = wave >> 1, wc = wave & 1;
    const int lq = lane & 15, lg = lane >> 4;

    f32x4 acc[4][4];
#pragma unroll
    for (int i = 0; i < 4; ++i)
#pragma unroll
        for (int j = 0; j < 4; ++j) acc[i][j] = (f32x4){0.f, 0.f, 0.f, 0.f};

    const int srow = tid >> 1;
    const int scol = (tid & 1) * 16;

    for (int kt = 0; kt < 16; ++kt) {
        const int k0 = kt * 32;
        if (kt) __syncthreads();
        {
            const float* g = X + (size_t)(rb + srow) * 512 + k0 + scol;
            float4 x0 = *(const float4*)(g + 0);
            float4 x1 = *(const float4*)(g + 4);
            float4 x2 = *(const float4*)(g + 8);
            float4 x3 = *(const float4*)(g + 12);
            uint4 w0, w1;
            w0.x = pk2(x0.x, x0.y); w0.y = pk2(x0.z, x0.w);
            w0.z = pk2(x1.x, x1.y); w0.w = pk2(x1.z, x1.w);
            w1.x = pk2(x2.x, x2.y); w1.y = pk2(x2.z, x2.w);
            w1.z = pk2(x3.x, x3.y); w1.w = pk2(x3.z, x3.w);
            *(uint4*)&lA[srow][scol] = w0;
            *(uint4*)&lA[srow][scol + 8] = w1;
        }
        {
            const float* g = Wz + (size_t)(nb + srow) * 512 + k0 + scol;
            float4 x0 = *(const float4*)(g + 0);
            float4 x1 = *(const float4*)(g + 4);
            float4 x2 = *(const float4*)(g + 8);
            float4 x3 = *(const float4*)(g + 12);
            uint4 w0, w1;
            w0.x = pk2(x0.x, x0.y); w0.y = pk2(x0.z, x0.w);
            w0.z = pk2(x1.x, x1.y); w0.w = pk2(x1.z, x1.w);
            w1.x = pk2(x2.x, x2.y); w1.y = pk2(x2.z, x2.w);
            w1.z = pk2(x3.x, x3.y); w1.w = pk2(x3.z, x3.w);
            *(uint4*)&lB[srow][scol] = w0;
            *(uint4*)&lB[srow][scol + 8] = w1;
        }
        __syncthreads();

        bf16x8 af[4], bf[4];
#pragma unroll
        for (int mi = 0; mi < 4; ++mi)
            af[mi] = *(const bf16x8*)&lA[wr * 64 + mi * 16 + lq][lg * 8];
#pragma unroll
        for (int ni = 0; ni < 4; ++ni)
            bf[ni] = *(const bf16x8*)&lB[wc * 64 + ni * 16 + lq][lg * 8];
#pragma unroll
        for (int mi = 0; mi < 4; ++mi)
#pragma unroll
            for (int ni = 0; ni < 4; ++ni)
                acc[mi][ni] = __builtin_amdgcn_mfma_f32_16x16x32_bf16(
                    af[mi], bf[ni], acc[mi][ni], 0, 0, 0);
    }

    const float* bz = bias + z * 512;
#pragma unroll
    for (int ni = 0; ni < 4; ++ni) {
        const int n = nb + wc * 64 + ni * 16 + lq;
        const float bv = bz[n];
        const int h = n >> 6, d = n & 63;
#pragma unroll
        for (int mi = 0; mi < 4; ++mi) {
#pragma unroll
            for (int r = 0; r < 4; ++r) {
                const int t = rb + wr * 64 + mi * 16 + lg * 4 + r;
                float v = acc[mi][ni][r] + bv;
                const int s = t >> 2, b = t & 3;
                if (z == 0) {
                    v *= 0.125f * L2E;
                    Qp[((size_t)(b * 8 + h) * 2048 + s) * 64 + d] = f2bf(v);
                } else if (z == 1) {
                    Kp[((size_t)(b * 8 + h) * 2048 + s) * 64 + d] = f2bf(v);
                } else {
                    Vt[((size_t)(b * 8 + h) * 64 + d) * 2048 + s] = f2bf(v);
                }
            }
        }
    }
}

// ---------------------------------------------------------------------------
// Kernel 0.5: mask -> bf16 fragment layout via LDS transpose (coalesced).
// grid (8 k-chunks of 256, 256 bq); 256 threads.  (verified R12)
// Mf[(bq*64+kt)*1024 + lane*16 + jj] =
//   mask[b][qt*32+(lane&31)][kt*32 + (jj&3)+8*(jj>>2)+4*(lane>>5)] * L2E
// ---------------------------------------------------------------------------
__global__ __launch_bounds__(256) void maskprep_kernel(
    const float* __restrict__ mask, unsigned short* __restrict__ Mf)
{
    __shared__ float lT[32][261];
    const int tid = threadIdx.x;
    const int bq = blockIdx.y;                  // b*64 + qt
    const int kx = blockIdx.x;                  // k-chunk of 256
    const float* base = mask + ((size_t)(bq >> 6) * 2048 + (bq & 63) * 32) * 2048
                        + (size_t)kx * 256;

    const int r = tid >> 3, ci = tid & 7;
    const float* rp = base + (size_t)r * 2048;
#pragma unroll
    for (int j = 0; j < 8; ++j) {
        const int c = (ci + j * 8) * 4;
        float4 v = *(const float4*)(rp + c);
        lT[r][c + 0] = v.x * L2E;
        lT[r][c + 1] = v.y * L2E;
        lT[r][c + 2] = v.z * L2E;
        lT[r][c + 3] = v.w * L2E;
    }
    __syncthreads();

    const int w = tid >> 6, lane = tid & 63;
    const int lc = lane & 31, hi = lane >> 5;
#pragma unroll
    for (int t = 0; t < 2; ++t) {
        const int ktl = w * 2 + t;
        float p[16];
#pragma unroll
        for (int jj = 0; jj < 16; ++jj)
            p[jj] = lT[lc][ktl * 32 + (jj & 3) + 8 * (jj >> 2) + 4 * hi];
        unsigned short* dst = Mf + ((size_t)bq * 64 + kx * 8 + ktl) * 1024 + lane * 16;
        *(uint4*)(dst) = make_uint4(pk2(p[0], p[1]), pk2(p[2], p[3]),
                                    pk2(p[4], p[5]), pk2(p[6], p[7]));
        *(uint4*)(dst + 8) = make_uint4(pk2(p[8], p[9]),  pk2(p[10], p[11]),
                                        pk2(p[12], p[13]), pk2(p[14], p[15]));
    }
}

// ---------------------------------------------------------------------------
// Kernel 1: flash attention, 32x32x16 MFMA, swapped QK^T, k-split 8 waves.
// grid (16 q-tiles of 128, 32 bh), 512 threads.
// wave w: qw = w&3 (q-subtile of 32 rows), kg = w>>2 (k-half).
// Per-group dbuf K/V LDS (XOR swizzle), 1 barrier/tile, reg prefetch.
// ---------------------------------------------------------------------------
#define SWAP32(a, b) asm("v_permlane32_swap_b32 %0, %1" : "+v"(a), "+v"(b))

#define COMPUTE(KC, VC, M) do {                                                \
    bf16x8 pf[4];                                                              \
    _Pragma("unroll")                                                          \
    for (int kblk = 0; kblk < 2; ++kblk) {                                     \
        f32x16 z;                                                              \
        {                                                                      \
            const uint4 m0 = M[kblk][0], m1 = M[kblk][1];                      \
            z[0]  = bflo(m0.x); z[1]  = bfhi(m0.x);                            \
            z[2]  = bflo(m0.y); z[3]  = bfhi(m0.y);                            \
            z[4]  = bflo(m0.z); z[5]  = bfhi(m0.z);                            \
            z[6]  = bflo(m0.w); z[7]  = bfhi(m0.w);                            \
            z[8]  = bflo(m1.x); z[9]  = bfhi(m1.x);                            \
            z[10] = bflo(m1.y); z[11] = bfhi(m1.y);                            \
            z[12] = bflo(m1.z); z[13] = bfhi(m1.z);                            \
            z[14] = bflo(m1.w); z[15] = bfhi(m1.w);                            \
        }                                                                      \
        __builtin_amdgcn_s_setprio(1);                                         \
        _Pragma("unroll")                                                      \
        for (int s = 0; s < 4; ++s) {                                          \
            bf16x8 kf = *(const bf16x8*)((KC) + fof[kblk][s]);                 \
            z = __builtin_amdgcn_mfma_f32_32x32x16_bf16(kf, qf[s], z, 0,0,0);  \
        }                                                                      \
        __builtin_amdgcn_s_setprio(0);                                         \
        float p[16];                                                           \
        _Pragma("unroll")                                                      \
        for (int i = 0; i < 16; ++i) p[i] = exp2f(z[i]);                       \
        lsum += (((p[0]+p[1])+(p[2]+p[3])) + ((p[4]+p[5])+(p[6]+p[7])))        \
              + (((p[8]+p[9])+(p[10]+p[11])) + ((p[12]+p[13])+(p[14]+p[15]))); \
        unsigned a0 = pk2(p[0], p[1]),   b0 = pk2(p[4], p[5]);                 \
        unsigned a1 = pk2(p[2], p[3]),   b1 = pk2(p[6], p[7]);                 \
        SWAP32(a0, b0); SWAP32(a1, b1);                                        \
        union { unsigned w[4]; bf16x8 v; } u0;                                 \
        u0.w[0] = a0; u0.w[1] = a1; u0.w[2] = b0; u0.w[3] = b1;                \
        pf[kblk*2] = u0.v;                                                     \
        unsigned c0 = pk2(p[8], p[9]),   d0 = pk2(p[12], p[13]);               \
        unsigned c1 = pk2(p[10], p[11]), d1 = pk2(p[14], p[15]);               \
        SWAP32(c0, d0); SWAP32(c1, d1);                                        \
        union { unsigned w[4]; bf16x8 v; } u1;                                 \
        u1.w[0] = c0; u1.w[1] = c1; u1.w[2] = d0; u1.w[3] = d1;                \
        pf[kblk*2+1] = u1.v;                                                   \
    }                                                                          \
    __builtin_amdgcn_s_setprio(1);                                             \
    _Pragma("unroll")                                                          \
    for (int s = 0; s < 4; ++s) {                                              \
        bf16x8 vf0 = *(const bf16x8*)((VC) + fof[0][s]);                       \
        o0 = __builtin_amdgcn_mfma_f32_32x32x16_bf16(vf0, pf[s], o0, 0,0,0);   \
        bf16x8 vf1 = *(const bf16x8*)((VC) + fof[1][s]);                       \
        o1 = __builtin_amdgcn_mfma_f32_32x32x16_bf16(vf1, pf[s], o1, 0,0,0);   \
    }                                                                          \
    __builtin_amdgcn_s_setprio(0);                                             \
} while (0)

#define LOADNEXT(MD) do {                                                      \
    ka = *(const uint4*)(pgK); kc = *(const uint4*)(pgK + 8);                  \
    va = *(const uint4*)(pgV); vc = *(const uint4*)(pgV + 8);                  \
    MD[0][0] = *(const uint4*)(pmf);                                           \
    MD[0][1] = *(const uint4*)(pmf + 8);                                       \
    MD[1][0] = *(const uint4*)(pmf + 1024);                                    \
    MD[1][1] = *(const uint4*)(pmf + 1032);                                    \
    pgK += 4096; pgV += 64; pmf += 2048;                                       \
} while (0)

#define STORE(BUF) do {                                                        \
    *(uint4*)&lK[kg][BUF][srow][su0 * 8] = ka;                                 \
    *(uint4*)&lK[kg][BUF][srow][su1 * 8] = kc;                                 \
    *(uint4*)&lV[kg][BUF][srow][su0 * 8] = va;                                 \
    *(uint4*)&lV[kg][BUF][srow][su1 * 8] = vc;                                 \
} while (0)

__global__ __launch_bounds__(512, 2) void attn_kernel(
    const unsigned short* __restrict__ Qp, const unsigned short* __restrict__ Kp,
    const unsigned short* __restrict__ Vt, const unsigned short* __restrict__ Mf,
    unsigned short* __restrict__ AO)
{
    __shared__ __align__(16) char smem[65536];
    unsigned short (*lK)[2][64][64] = (unsigned short (*)[2][64][64])(smem);
    unsigned short (*lV)[2][64][64] = (unsigned short (*)[2][64][64])(smem + 32768);
    float* ex = (float*)smem;   // reused after compute for the O exchange

    const int bh = blockIdx.y;
    const int b = bh >> 3, h = bh & 7;
    const int qb = blockIdx.x * 128;
    const int tid  = threadIdx.x;
    const int lane = tid & 63, wave = tid >> 6;
    const int qw = wave & 3, kg = wave >> 2;
    const int lc = lane & 31, hi = lane >> 5;
    const int qg = qb + qw * 32 + lc;

    // Q B-fragments: lane needs Q[qg][s*16 + hi*8 + 0..7]
    bf16x8 qf[4];
    {
        const unsigned short* qp = Qp + ((size_t)bh * 2048 + qg) * 64 + hi * 8;
#pragma unroll
        for (int s = 0; s < 4; ++s)
            qf[s] = *(const bf16x8*)(qp + s * 16);
    }

    f32x16 o0, o1;
#pragma unroll
    for (int i = 0; i < 16; ++i) { o0[i] = 0.f; o1[i] = 0.f; }
    float lsum = 0.f;

    // K/V fragment byte-offsets in one group's [64][64]-short tile:
    // row = blk*32 + lc; 16B-unit = (2s|hi) ^ (row&7)
    int fof[2][4];
#pragma unroll
    for (int blk = 0; blk < 2; ++blk)
#pragma unroll
        for (int s = 0; s < 4; ++s)
            fof[blk][s] = (blk * 32 + lc) * 128 +
                          ((((s << 1) | hi) ^ (lane & 7)) * 16);

    const char* lK0c = (const char*)&lK[kg][0][0][0];
    const char* lK1c = (const char*)&lK[kg][1][0][0];
    const char* lV0c = (const char*)&lV[kg][0][0][0];
    const char* lV1c = (const char*)&lV[kg][1][0][0];

    // staging: each group's 256 threads stage that group's K/V tile pair
    const int gtid = tid & 255;
    const int srow = gtid >> 2;
    const int scu  = (gtid & 3) * 2;
    const int su0  = (scu    ) ^ (srow & 7);
    const int su1  = (scu + 1) ^ (srow & 7);
    const unsigned short* pgK = Kp + (size_t)bh * 2048 * 64
                                + (size_t)(kg * 1024 + srow) * 64 + scu * 8;
    const unsigned short* pgV = Vt + (size_t)bh * 64 * 2048
                                + (size_t)srow * 2048 + kg * 1024 + scu * 8;
    // group kg covers kt tiles [kg*32, kg*32+31] (1024 k / 32 per kt tile)
    const unsigned short* pmf = Mf +
        ((size_t)(b * 64 + (qb >> 5) + qw) * 64 + kg * 32) * 1024 + lane * 16;

    uint4 ka, kc, va, vc;
    uint4 mA[2][2], mB[2][2];

    LOADNEXT(mA);
    STORE(0);
    __syncthreads();

    for (int kb2 = 0; kb2 < 8; ++kb2) {
        {
            LOADNEXT(mB);
            COMPUTE(lK0c, lV0c, mA);
            STORE(1);
            __syncthreads();
        }
        {
            if (kb2 < 7) LOADNEXT(mA);
            COMPUTE(lK1c, lV1c, mB);
            if (kb2 < 7) {
                STORE(0);
                __syncthreads();
            }
        }
    }
    __syncthreads();    // all waves done with K/V LDS; safe to reuse as ex

    // within-wave: halves (lane, lane^32) hold disjoint k partials
    lsum += __shfl_xor(lsum, 32);

    // cross-group exchange: wave writes its OTHER d-half + lsum, stride 18 f32
    {
        float* slot = ex + ((size_t)wave * 64 + lane) * 18;
        if (kg == 0) {
#pragma unroll
            for (int i = 0; i < 8; ++i)
                *(float2*)(slot + 2 * i) = make_float2(o1[2*i], o1[2*i+1]);
        } else {
#pragma unroll
            for (int i = 0; i < 8; ++i)
                *(float2*)(slot + 2 * i) = make_float2(o0[2*i], o0[2*i+1]);
        }
        slot[16] = lsum;
    }
    __syncthreads();

    const float* pslot = ex + ((size_t)(wave ^ 4) * 64 + lane) * 18;
    const float lt = lsum + pslot[16];
    const float inv = 1.0f / lt;

    unsigned short* ao = AO + ((size_t)qg * 4 + b) * 512 + h * 64;
    if (kg == 0) {
#pragma unroll
        for (int g = 0; g < 4; ++g) {
            const int d0 = g * 8 + hi * 4;
            float s0 = (o0[4*g+0] + pslot[4*g+0]) * inv;
            float s1 = (o0[4*g+1] + pslot[4*g+1]) * inv;
            float s2 = (o0[4*g+2] + pslot[4*g+2]) * inv;
            float s3 = (o0[4*g+3] + pslot[4*g+3]) * inv;
            *(uint2*)(ao + d0) = make_uint2(pk2(s0, s1), pk2(s2, s3));
        }
    } else {
#pragma unroll
        for (int g = 0; g < 4; ++g) {
            const int d0 = g * 8 + hi * 4;
            float s0 = (o1[4*g+0] + pslot[4*g+0]) * inv;
            float s1 = (o1[4*g+1] + pslot[4*g+1]) * inv;
            float s2 = (o1[4*g+2] + pslot[4*g+2]) * inv;
            float s3 = (o1[4*g+3] + pslot[4*g+3]) * inv;
            *(uint2*)(ao + 32 + d0) = make_uint2(pk2(s0, s1), pk2(s2, s3));
        }
    }
}

// ---------------------------------------------------------------------------
// Kernel 2: output projection. out = AO(bf16) @ W_out^T + b_out (fp32 out).
// ---------------------------------------------------------------------------
__global__ __launch_bounds__(256) void oproj_kernel(
    const unsigned short* __restrict__ A, const float* __restrict__ W,
    const float* __restrict__ bias, float* __restrict__ out)
{
    __shared__ unsigned short lA[128][40];
    __shared__ unsigned short lB[128][40];

    const int rb = blockIdx.y * 128;
    const int nb = blockIdx.x * 128;
    const int tid  = threadIdx.x;
    const int lane = tid & 63, wave = tid >> 6;
    const int wr = wave >> 1, wc = wave & 1;
    const int lq = lane & 15, lg = lane >> 4;

    f32x4 acc[4][4];
#pragma unroll
    for (int i = 0; i < 4; ++i)
#pragma unroll
        for (int j = 0; j < 4; ++j) acc[i][j] = (f32x4){0.f, 0.f, 0.f, 0.f};

    const int srow = tid >> 1;
    const int scol = (tid & 1) * 16;

    for (int kt = 0; kt < 16; ++kt) {
        const int k0 = kt * 32;
        if (kt) __syncthreads();
        {
            const unsigned short* g = A + (size_t)(rb + srow) * 512 + k0 + scol;
            *(uint4*)&lA[srow][scol]     = *(const uint4*)g;
            *(uint4*)&lA[srow][scol + 8] = *(const uint4*)(g + 8);
        }
        {
            const float* g = W + (size_t)(nb + srow) * 512 + k0 + scol;
            float4 x0 = *(const float4*)(g + 0);
            float4 x1 = *(const float4*)(g + 4);
            float4 x2 = *(const float4*)(g + 8);
            float4 x3 = *(const float4*)(g + 12);
            uint4 w0, w1;
            w0.x = pk2(x0.x, x0.y); w0.y = pk2(x0.z, x0.w);
            w0.z = pk2(x1.x, x1.y); w0.w = pk2(x1.z, x1.w);
            w1.x = pk2(x2.x, x2.y); w1.y = pk2(x2.z, x2.w);
            w1.z = pk2(x3.x, x3.y); w1.w = pk2(x3.z, x3.w);
            *(uint4*)&lB[srow][scol] = w0;
            *(uint4*)&lB[srow][scol + 8] = w1;
        }
        __syncthreads();

        bf16x8 af[4], bfr[4];
#pragma unroll
        for (int mi = 0; mi < 4; ++mi)
            af[mi] = *(const bf16x8*)&lA[wr * 64 + mi * 16 + lq][lg * 8];
#pragma unroll
        for (int ni = 0; ni < 4; ++ni)
            bfr[ni] = *(const bf16x8*)&lB[wc * 64 + ni * 16 + lq][lg * 8];
#pragma unroll
        for (int mi = 0; mi < 4; ++mi)
#pragma unroll
            for (int ni = 0; ni < 4; ++ni)
                acc[mi][ni] = __builtin_amdgcn_mfma_f32_16x16x32_bf16(
                    af[mi], bfr[ni], acc[mi][ni], 0, 0, 0);
    }

#pragma unroll
    for (int ni = 0; ni < 4; ++ni) {
        const int n = nb + wc * 64 + ni * 16 + lq;
        const float bv = bias[n];
#pragma unroll
        for (int mi = 0; mi < 4; ++mi) {
#pragma unroll
            for (int r = 0; r < 4; ++r) {
                const int t = rb + wr * 64 + mi * 16 + lg * 4 + r;
                out[(size_t)t * 512 + n] = acc[mi][ni][r] + bv;
            }
        }
    }
}

extern "C" void kernel_launch(void* const* d_in, const int* in_sizes, int n_in,
                              void* d_out, int out_size, void* d_ws, size_t ws_size,
                              hipStream_t stream)
{
    (void)in_sizes; (void)n_in; (void)out_size; (void)ws_size;
    const float* query = (const float*)d_in[0];
    const float* key   = (const float*)d_in[1];
    const float* value = (const float*)d_in[2];
    const float* mask  = (const float*)d_in[3];
    const float* w_in  = (const float*)d_in[4];
    const float* b_in  = (const float*)d_in[5];
    const float* w_out = (const float*)d_in[6];
    const float* b_out = (const float*)d_in[7];
    float* out = (float*)d_out;

    char* ws = (char*)d_ws;
    unsigned short* Qp = (unsigned short*)(ws);                            // [32][2048][64]
    unsigned short* Kp = (unsigned short*)(ws + (size_t)8 * 1024 * 1024);  // [32][2048][64]
    unsigned short* Vt = (unsigned short*)(ws + (size_t)16 * 1024 * 1024); // [32][64][2048]
    unsigned short* AO = (unsigned short*)(ws + (size_t)24 * 1024 * 1024); // [8192][512]
    unsigned short* Mf = (unsigned short*)(ws + (size_t)32 * 1024 * 1024); // [4][64][64][64][16]

    qkv_kernel<<<dim3(4, 64, 3), 256, 0, stream>>>(query, key, value, w_in, b_in,
                                                   Qp, Kp, Vt);
    maskprep_kernel<<<dim3(8, 256), 256, 0, stream>>>(mask, Mf);
    attn_kernel<<<dim3(16, 32), 512, 0, stream>>>(Qp, Kp, Vt, Mf, AO);
    oproj_kernel<<<dim3(4, 64), 256, 0, stream>>>(AO, w_out, b_out, out);
}

// Round 15
// 153.214 us; speedup vs baseline: 1.7535x; 1.0394x over previous
//
#include <hip/hip_runtime.h>

// MHA forward: S=2048, B=4, E=512, H=8, D=64.
// qkvmask_kernel (qkv GEMMs + mask fragment prep merged, independent work
// overlapped in one launch) -> attn_kernel (block-level k-split: grid z=kg,
// fp32 partial O + lsum to workspace) -> reduce_kernel -> oproj_kernel.
// R15: R14 showed the occupancy limiter is the GRID (512 blocks = 2/CU);
// block-level k-split gives 1024 x 256-thr blocks (4/CU, 16 waves/CU) with
// NO intra-block exchange. k-offsets proven by R13/R14 PASS; COMPUTE is
// R12's verified arithmetic (exp2f + native pk2; no inline-asm exp).

#define L2E 1.44269504088896340736f

typedef __attribute__((ext_vector_type(8))) __bf16 bf16x8;
typedef __attribute__((ext_vector_type(4))) float f32x4;
typedef __attribute__((ext_vector_type(16))) float f32x16;

static __device__ __forceinline__ unsigned pk2(float a, float b) {
    union { unsigned u; __bf16 h[2]; } cv;
    cv.h[0] = (__bf16)a; cv.h[1] = (__bf16)b;
    return cv.u;
}

static __device__ __forceinline__ unsigned short f2bf(float f) {
    union { unsigned short s; __bf16 h; } cv;
    cv.h = (__bf16)f;
    return cv.s;
}

static __device__ __forceinline__ float bflo(unsigned u) {
    union { unsigned u; float f; } cv; cv.u = u << 16; return cv.f;
}
static __device__ __forceinline__ float bfhi(unsigned u) {
    union { unsigned u; float f; } cv; cv.u = u & 0xFFFF0000u; return cv.f;
}

// ---------------------------------------------------------------------------
// Kernel 0: merged qkv projection + mask fragment prep (independent work).
// 1D grid of 768 + 2048 = 2816 blocks, 256 threads.
//   id < 768:  qkv. x=id&3 (n-tile), y=(id>>2)&63 (m-tile), z=id>>8 (q/k/v).
//              z=0 -> Qp (scaled L2E/8), z=1 -> Kp, z=2 -> Vt[bh][d][s].
//   id >= 768: maskprep. m=id-768: kx=m&7 (k-chunk of 256), bq=m>>3.
//              Mf[(bq*64+kt)*1024 + lane*16 + jj] =
//                mask[b][qt*32+(lane&31)][kt*32+(jj&3)+8*(jj>>2)+4*(lane>>5)]*L2E
// ---------------------------------------------------------------------------
__global__ __launch_bounds__(256) void qkvmask_kernel(
    const float* __restrict__ Xq, const float* __restrict__ Xk,
    const float* __restrict__ Xv, const float* __restrict__ W,
    const float* __restrict__ bias, const float* __restrict__ mask,
    unsigned short* __restrict__ Qp, unsigned short* __restrict__ Kp,
    unsigned short* __restrict__ Vt, unsigned short* __restrict__ Mf)
{
    __shared__ __align__(16) char smem[33408];   // max(qkv 20480, maskprep 33408)
    const int id = blockIdx.x;
    const int tid = threadIdx.x;

    if (id < 768) {
        // ----------------- qkv GEMM path -----------------
        unsigned short (*lA)[40] = (unsigned short (*)[40])smem;
        unsigned short (*lB)[40] = (unsigned short (*)[40])(smem + 10240);

        const int z = id >> 8;
        const float* X  = (z == 0) ? Xq : (z == 1) ? Xk : Xv;
        const float* Wz = W + (size_t)z * 512 * 512;
        const int rb = ((id >> 2) & 63) * 128;
        const int nb = (id & 3) * 128;
        const int lane = tid & 63, wave = tid >> 6;
        const int wr = wave >> 1, wc = wave & 1;
        const int lq = lane & 15, lg = lane >> 4;

        f32x4 acc[4][4];
#pragma unroll
        for (int i = 0; i < 4; ++i)
#pragma unroll
            for (int j = 0; j < 4; ++j) acc[i][j] = (f32x4){0.f, 0.f, 0.f, 0.f};

        const int srow = tid >> 1;
        const int scol = (tid & 1) * 16;

        for (int kt = 0; kt < 16; ++kt) {
            const int k0 = kt * 32;
            if (kt) __syncthreads();
            {
                const float* g = X + (size_t)(rb + srow) * 512 + k0 + scol;
                float4 x0 = *(const float4*)(g + 0);
                float4 x1 = *(const float4*)(g + 4);
                float4 x2 = *(const float4*)(g + 8);
                float4 x3 = *(const float4*)(g + 12);
                uint4 w0, w1;
                w0.x = pk2(x0.x, x0.y); w0.y = pk2(x0.z, x0.w);
                w0.z = pk2(x1.x, x1.y); w0.w = pk2(x1.z, x1.w);
                w1.x = pk2(x2.x, x2.y); w1.y = pk2(x2.z, x2.w);
                w1.z = pk2(x3.x, x3.y); w1.w = pk2(x3.z, x3.w);
                *(uint4*)&lA[srow][scol] = w0;
                *(uint4*)&lA[srow][scol + 8] = w1;
            }
            {
                const float* g = Wz + (size_t)(nb + srow) * 512 + k0 + scol;
                float4 x0 = *(const float4*)(g + 0);
                float4 x1 = *(const float4*)(g + 4);
                float4 x2 = *(const float4*)(g + 8);
                float4 x3 = *(const float4*)(g + 12);
                uint4 w0, w1;
                w0.x = pk2(x0.x, x0.y); w0.y = pk2(x0.z, x0.w);
                w0.z = pk2(x1.x, x1.y); w0.w = pk2(x1.z, x1.w);
                w1.x = pk2(x2.x, x2.y); w1.y = pk2(x2.z, x2.w);
                w1.z = pk2(x3.x, x3.y); w1.w = pk2(x3.z, x3.w);
                *(uint4*)&lB[srow][scol] = w0;
                *(uint4*)&lB[srow][scol + 8] = w1;
            }
            __syncthreads();

            bf16x8 af[4], bf[4];
#pragma unroll
            for (int mi = 0; mi < 4; ++mi)
                af[mi] = *(const bf16x8*)&lA[wr * 64 + mi * 16 + lq][lg * 8];
#pragma unroll
            for (int ni = 0; ni < 4; ++ni)
                bf[ni] = *(const bf16x8*)&lB[wc * 64 + ni * 16 + lq][lg * 8];
#pragma unroll
            for (int mi = 0; mi < 4; ++mi)
#pragma unroll
                for (int ni = 0; ni < 4; ++ni)
                    acc[mi][ni] = __builtin_amdgcn_mfma_f32_16x16x32_bf16(
                        af[mi], bf[ni], acc[mi][ni], 0, 0, 0);
        }

        const float* bz = bias + z * 512;
#pragma unroll
        for (int ni = 0; ni < 4; ++ni) {
            const int n = nb + wc * 64 + ni * 16 + lq;
            const float bv = bz[n];
            const int h = n >> 6, d = n & 63;
#pragma unroll
            for (int mi = 0; mi < 4; ++mi) {
#pragma unroll
                for (int r = 0; r < 4; ++r) {
                    const int t = rb + wr * 64 + mi * 16 + lg * 4 + r;
                    float v = acc[mi][ni][r] + bv;
                    const int s = t >> 2, b = t & 3;
                    if (z == 0) {
                        v *= 0.125f * L2E;
                        Qp[((size_t)(b * 8 + h) * 2048 + s) * 64 + d] = f2bf(v);
                    } else if (z == 1) {
                        Kp[((size_t)(b * 8 + h) * 2048 + s) * 64 + d] = f2bf(v);
                    } else {
                        Vt[((size_t)(b * 8 + h) * 64 + d) * 2048 + s] = f2bf(v);
                    }
                }
            }
        }
    } else {
        // ----------------- maskprep path (verified R12) -----------------
        float (*lT)[261] = (float (*)[261])smem;
        const int m = id - 768;
        const int kx = m & 7;
        const int bq = m >> 3;
        const float* base = mask + ((size_t)(bq >> 6) * 2048 + (bq & 63) * 32) * 2048
                            + (size_t)kx * 256;

        const int r = tid >> 3, ci = tid & 7;
        const float* rp = base + (size_t)r * 2048;
#pragma unroll
        for (int j = 0; j < 8; ++j) {
            const int c = (ci + j * 8) * 4;
            float4 v = *(const float4*)(rp + c);
            lT[r][c + 0] = v.x * L2E;
            lT[r][c + 1] = v.y * L2E;
            lT[r][c + 2] = v.z * L2E;
            lT[r][c + 3] = v.w * L2E;
        }
        __syncthreads();

        const int w = tid >> 6, lane = tid & 63;
        const int lc = lane & 31, hi = lane >> 5;
#pragma unroll
        for (int t = 0; t < 2; ++t) {
            const int ktl = w * 2 + t;
            float p[16];
#pragma unroll
            for (int jj = 0; jj < 16; ++jj)
                p[jj] = lT[lc][ktl * 32 + (jj & 3) + 8 * (jj >> 2) + 4 * hi];
            unsigned short* dst = Mf + ((size_t)bq * 64 + kx * 8 + ktl) * 1024 + lane * 16;
            *(uint4*)(dst) = make_uint4(pk2(p[0], p[1]), pk2(p[2], p[3]),
                                        pk2(p[4], p[5]), pk2(p[6], p[7]));
            *(uint4*)(dst + 8) = make_uint4(pk2(p[8], p[9]),  pk2(p[10], p[11]),
                                            pk2(p[12], p[13]), pk2(p[14], p[15]));
        }
    }
}

// ---------------------------------------------------------------------------
// Kernel 1: flash attention, 32x32x16 MFMA, swapped QK^T, block-level k-split.
// grid (16 q-tiles of 128, 32 bh, 2 kg), 256 threads, 4 waves x 32 q-rows.
// Block (.,.,kg) covers k in [kg*1024, kg*1024+1024) (16 x 64-k tiles) and
// writes fp32 partial O to Op[kg] and per-q partial lsum to Ls[kg].
// K/V dbuf LDS (XOR swizzle), 1 barrier/tile, reg prefetch, kb-loop x2.
// ---------------------------------------------------------------------------
#define SWAP32(a, b) asm("v_permlane32_swap_b32 %0, %1" : "+v"(a), "+v"(b))

#define COMPUTE(KC, VC, M) do {                                                \
    bf16x8 pf[4];                                                              \
    _Pragma("unroll")                                                          \
    for (int kblk = 0; kblk < 2; ++kblk) {                                     \
        f32x16 z;                                                              \
        {                                                                      \
            const uint4 m0 = M[kblk][0], m1 = M[kblk][1];                      \
            z[0]  = bflo(m0.x); z[1]  = bfhi(m0.x);                            \
            z[2]  = bflo(m0.y); z[3]  = bfhi(m0.y);                            \
            z[4]  = bflo(m0.z); z[5]  = bfhi(m0.z);                            \
            z[6]  = bflo(m0.w); z[7]  = bfhi(m0.w);                            \
            z[8]  = bflo(m1.x); z[9]  = bfhi(m1.x);                            \
            z[10] = bflo(m1.y); z[11] = bfhi(m1.y);                            \
            z[12] = bflo(m1.z); z[13] = bfhi(m1.z);                            \
            z[14] = bflo(m1.w); z[15] = bfhi(m1.w);                            \
        }                                                                      \
        __builtin_amdgcn_s_setprio(1);                                         \
        _Pragma("unroll")                                                      \
        for (int s = 0; s < 4; ++s) {                                          \
            bf16x8 kf = *(const bf16x8*)((KC) + fof[kblk][s]);                 \
            z = __builtin_amdgcn_mfma_f32_32x32x16_bf16(kf, qf[s], z, 0,0,0);  \
        }                                                                      \
        __builtin_amdgcn_s_setprio(0);                                         \
        float p[16];                                                           \
        _Pragma("unroll")                                                      \
        for (int i = 0; i < 16; ++i) p[i] = exp2f(z[i]);                       \
        lsum += (((p[0]+p[1])+(p[2]+p[3])) + ((p[4]+p[5])+(p[6]+p[7])))        \
              + (((p[8]+p[9])+(p[10]+p[11])) + ((p[12]+p[13])+(p[14]+p[15]))); \
        unsigned a0 = pk2(p[0], p[1]),   b0 = pk2(p[4], p[5]);                 \
        unsigned a1 = pk2(p[2], p[3]),   b1 = pk2(p[6], p[7]);                 \
        SWAP32(a0, b0); SWAP32(a1, b1);                                        \
        union { unsigned w[4]; bf16x8 v; } u0;                                 \
        u0.w[0] = a0; u0.w[1] = a1; u0.w[2] = b0; u0.w[3] = b1;                \
        pf[kblk*2] = u0.v;                                                     \
        unsigned c0 = pk2(p[8], p[9]),   d0 = pk2(p[12], p[13]);               \
        unsigned c1 = pk2(p[10], p[11]), d1 = pk2(p[14], p[15]);               \
        SWAP32(c0, d0); SWAP32(c1, d1);                                        \
        union { unsigned w[4]; bf16x8 v; } u1;                                 \
        u1.w[0] = c0; u1.w[1] = c1; u1.w[2] = d0; u1.w[3] = d1;                \
        pf[kblk*2+1] = u1.v;                                                   \
    }                                                                          \
    __builtin_amdgcn_s_setprio(1);                                             \
    _Pragma("unroll")                                                          \
    for (int s = 0; s < 4; ++s) {                                              \
        bf16x8 vf0 = *(const bf16x8*)((VC) + fof[0][s]);                       \
        o0 = __builtin_amdgcn_mfma_f32_32x32x16_bf16(vf0, pf[s], o0, 0,0,0);   \
        bf16x8 vf1 = *(const bf16x8*)((VC) + fof[1][s]);                       \
        o1 = __builtin_amdgcn_mfma_f32_32x32x16_bf16(vf1, pf[s], o1, 0,0,0);   \
    }                                                                          \
    __builtin_amdgcn_s_setprio(0);                                             \
} while (0)

#define LOADNEXT(MD) do {                                                      \
    ka = *(const uint4*)(pgK); kc = *(const uint4*)(pgK + 8);                  \
    va = *(const uint4*)(pgV); vc = *(const uint4*)(pgV + 8);                  \
    MD[0][0] = *(const uint4*)(pmf);                                           \
    MD[0][1] = *(const uint4*)(pmf + 8);                                       \
    MD[1][0] = *(const uint4*)(pmf + 1024);                                    \
    MD[1][1] = *(const uint4*)(pmf + 1032);                                    \
    pgK += 4096; pgV += 64; pmf += 2048;                                       \
} while (0)

#define STORE(BUF) do {                                                        \
    *(uint4*)&lK[BUF][srow][su0 * 8] = ka;                                     \
    *(uint4*)&lK[BUF][srow][su1 * 8] = kc;                                     \
    *(uint4*)&lV[BUF][srow][su0 * 8] = va;                                     \
    *(uint4*)&lV[BUF][srow][su1 * 8] = vc;                                     \
} while (0)

__global__ __launch_bounds__(256, 2) void attn_kernel(
    const unsigned short* __restrict__ Qp, const unsigned short* __restrict__ Kp,
    const unsigned short* __restrict__ Vt, const unsigned short* __restrict__ Mf,
    float* __restrict__ Op, float* __restrict__ Ls)
{
    __shared__ unsigned short lK[2][64][64];   // [buf][k][d], swizzled 16B units
    __shared__ unsigned short lV[2][64][64];   // [buf][d][k], same swizzle

    const int bh = blockIdx.y;
    const int b = bh >> 3, h = bh & 7;
    const int qb = blockIdx.x * 128;
    const int kg = blockIdx.z;                 // k-half: [kg*1024, +1024)
    const int tid  = threadIdx.x;
    const int lane = tid & 63, wave = tid >> 6;
    const int lc = lane & 31, hi = lane >> 5;
    const int qg = qb + wave * 32 + lc;

    bf16x8 qf[4];
    {
        const unsigned short* qp = Qp + ((size_t)bh * 2048 + qg) * 64 + hi * 8;
#pragma unroll
        for (int s = 0; s < 4; ++s)
            qf[s] = *(const bf16x8*)(qp + s * 16);
    }

    f32x16 o0, o1;
#pragma unroll
    for (int i = 0; i < 16; ++i) { o0[i] = 0.f; o1[i] = 0.f; }
    float lsum = 0.f;

    int fof[2][4];
#pragma unroll
    for (int blk = 0; blk < 2; ++blk)
#pragma unroll
        for (int s = 0; s < 4; ++s)
            fof[blk][s] = (blk * 32 + lc) * 128 +
                          ((((s << 1) | hi) ^ (lane & 7)) * 16);

    const char* lK0c = (const char*)&lK[0][0][0];
    const char* lK1c = (const char*)&lK[1][0][0];
    const char* lV0c = (const char*)&lV[0][0][0];
    const char* lV1c = (const char*)&lV[1][0][0];

    const int srow = tid >> 2;
    const int scu  = (tid & 3) * 2;
    const int su0  = (scu    ) ^ (srow & 7);
    const int su1  = (scu + 1) ^ (srow & 7);
    const unsigned short* pgK = Kp + (size_t)bh * 2048 * 64
                                + (size_t)(kg * 1024 + srow) * 64 + scu * 8;
    const unsigned short* pgV = Vt + (size_t)bh * 64 * 2048
                                + (size_t)srow * 2048 + kg * 1024 + scu * 8;
    // group kg covers kt tiles [kg*32, kg*32+31] (proven R13/R14)
    const unsigned short* pmf = Mf +
        ((size_t)(b * 64 + (qb >> 5) + wave) * 64 + kg * 32) * 1024 + lane * 16;

    uint4 ka, kc, va, vc;
    uint4 mA[2][2], mB[2][2];

    LOADNEXT(mA);
    STORE(0);
    __syncthreads();

    for (int kb2 = 0; kb2 < 8; ++kb2) {
        {
            LOADNEXT(mB);
            COMPUTE(lK0c, lV0c, mA);
            STORE(1);
            __syncthreads();
        }
        {
            if (kb2 < 7) LOADNEXT(mA);
            COMPUTE(lK1c, lV1c, mB);
            if (kb2 < 7) {
                STORE(0);
                __syncthreads();
            }
        }
    }

    // halves (lane, lane^32) hold disjoint k partials for q=lc
    lsum += __shfl_xor(lsum, 32);

    // write fp32 partials: Op[kg][(qg*4+b)*512 + h*64 + d], Ls[kg][bh*2048+qg]
    float* op = Op + (size_t)kg * 4194304 + ((size_t)qg * 4 + b) * 512 + h * 64;
#pragma unroll
    for (int g = 0; g < 4; ++g) {
        const int d0 = g * 8 + hi * 4;
        *(float4*)(op + d0)      = make_float4(o0[4*g+0], o0[4*g+1], o0[4*g+2], o0[4*g+3]);
        *(float4*)(op + 32 + d0) = make_float4(o1[4*g+0], o1[4*g+1], o1[4*g+2], o1[4*g+3]);
    }
    if (lane < 32)
        Ls[(size_t)kg * 65536 + (size_t)bh * 2048 + qg] = lsum;
}

// ---------------------------------------------------------------------------
// Kernel 1.5: combine k-split partials -> AO bf16.
// AO[i] = (Op0[i]+Op1[i]) / (Ls0[bh,q]+Ls1[bh,q]); i = (qg*4+b)*512+h*64+d.
// grid 4096 x 256, float4 per thread.
// ---------------------------------------------------------------------------
__global__ __launch_bounds__(256) void reduce_kernel(
    const float* __restrict__ Op, const float* __restrict__ Ls,
    unsigned short* __restrict__ AO)
{
    const int i4 = blockIdx.x * 256 + threadIdx.x;
    const int i = i4 * 4;
    const int qg = i >> 11;
    const int bh = (((i >> 9) & 3) << 3) | ((i >> 6) & 7);
    const float l = Ls[(size_t)bh * 2048 + qg] + Ls[65536 + (size_t)bh * 2048 + qg];
    const float inv = 1.0f / l;
    float4 a = *(const float4*)(Op + i);
    float4 c = *(const float4*)(Op + 4194304 + i);
    *(uint2*)(AO + i) = make_uint2(pk2((a.x + c.x) * inv, (a.y + c.y) * inv),
                                   pk2((a.z + c.z) * inv, (a.w + c.w) * inv));
}

// ---------------------------------------------------------------------------
// Kernel 2: output projection. out = AO(bf16) @ W_out^T + b_out (fp32 out).
// ---------------------------------------------------------------------------
__global__ __launch_bounds__(256) void oproj_kernel(
    const unsigned short* __restrict__ A, const float* __restrict__ W,
    const float* __restrict__ bias, float* __restrict__ out)
{
    __shared__ unsigned short lA[128][40];
    __shared__ unsigned short lB[128][40];

    const int rb = blockIdx.y * 128;
    const int nb = blockIdx.x * 128;
    const int tid  = threadIdx.x;
    const int lane = tid & 63, wave = tid >> 6;
    const int wr = wave >> 1, wc = wave & 1;
    const int lq = lane & 15, lg = lane >> 4;

    f32x4 acc[4][4];
#pragma unroll
    for (int i = 0; i < 4; ++i)
#pragma unroll
        for (int j = 0; j < 4; ++j) acc[i][j] = (f32x4){0.f, 0.f, 0.f, 0.f};

    const int srow = tid >> 1;
    const int scol = (tid & 1) * 16;

    for (int kt = 0; kt < 16; ++kt) {
        const int k0 = kt * 32;
        if (kt) __syncthreads();
        {
            const unsigned short* g = A + (size_t)(rb + srow) * 512 + k0 + scol;
            *(uint4*)&lA[srow][scol]     = *(const uint4*)g;
            *(uint4*)&lA[srow][scol + 8] = *(const uint4*)(g + 8);
        }
        {
            const float* g = W + (size_t)(nb + srow) * 512 + k0 + scol;
            float4 x0 = *(const float4*)(g + 0);
            float4 x1 = *(const float4*)(g + 4);
            float4 x2 = *(const float4*)(g + 8);
            float4 x3 = *(const float4*)(g + 12);
            uint4 w0, w1;
            w0.x = pk2(x0.x, x0.y); w0.y = pk2(x0.z, x0.w);
            w0.z = pk2(x1.x, x1.y); w0.w = pk2(x1.z, x1.w);
            w1.x = pk2(x2.x, x2.y); w1.y = pk2(x2.z, x2.w);
            w1.z = pk2(x3.x, x3.y); w1.w = pk2(x3.z, x3.w);
            *(uint4*)&lB[srow][scol] = w0;
            *(uint4*)&lB[srow][scol + 8] = w1;
        }
        __syncthreads();

        bf16x8 af[4], bfr[4];
#pragma unroll
        for (int mi = 0; mi < 4; ++mi)
            af[mi] = *(const bf16x8*)&lA[wr * 64 + mi * 16 + lq][lg * 8];
#pragma unroll
        for (int ni = 0; ni < 4; ++ni)
            bfr[ni] = *(const bf16x8*)&lB[wc * 64 + ni * 16 + lq][lg * 8];
#pragma unroll
        for (int mi = 0; mi < 4; ++mi)
#pragma unroll
            for (int ni = 0; ni < 4; ++ni)
                acc[mi][ni] = __builtin_amdgcn_mfma_f32_16x16x32_bf16(
                    af[mi], bfr[ni], acc[mi][ni], 0, 0, 0);
    }

#pragma unroll
    for (int ni = 0; ni < 4; ++ni) {
        const int n = nb + wc * 64 + ni * 16 + lq;
        const float bv = bias[n];
#pragma unroll
        for (int mi = 0; mi < 4; ++mi) {
#pragma unroll
            for (int r = 0; r < 4; ++r) {
                const int t = rb + wr * 64 + mi * 16 + lg * 4 + r;
                out[(size_t)t * 512 + n] = acc[mi][ni][r] + bv;
            }
        }
    }
}

extern "C" void kernel_launch(void* const* d_in, const int* in_sizes, int n_in,
                              void* d_out, int out_size, void* d_ws, size_t ws_size,
                              hipStream_t stream)
{
    (void)in_sizes; (void)n_in; (void)out_size; (void)ws_size;
    const float* query = (const float*)d_in[0];
    const float* key   = (const float*)d_in[1];
    const float* value = (const float*)d_in[2];
    const float* mask  = (const float*)d_in[3];
    const float* w_in  = (const float*)d_in[4];
    const float* b_in  = (const float*)d_in[5];
    const float* w_out = (const float*)d_in[6];
    const float* b_out = (const float*)d_in[7];
    float* out = (float*)d_out;

    char* ws = (char*)d_ws;
    const size_t MB = 1024 * 1024;
    unsigned short* Qp = (unsigned short*)(ws);            // [32][2048][64] bf16, 8 MB
    unsigned short* Kp = (unsigned short*)(ws + 8 * MB);   // 8 MB
    unsigned short* Vt = (unsigned short*)(ws + 16 * MB);  // [32][64][2048], 8 MB
    unsigned short* AO = (unsigned short*)(ws + 24 * MB);  // [8192][512] bf16, 8 MB
    unsigned short* Mf = (unsigned short*)(ws + 32 * MB);  // mask fragments, 32 MB
    float*          Op = (float*)(ws + 64 * MB);           // [2][8192][512] f32, 32 MB
    float*          Ls = (float*)(ws + 96 * MB);           // [2][32][2048] f32, 512 KB

    qkvmask_kernel<<<dim3(2816), 256, 0, stream>>>(query, key, value, w_in, b_in,
                                                   mask, Qp, Kp, Vt, Mf);
    attn_kernel<<<dim3(16, 32, 2), 256, 0, stream>>>(Qp, Kp, Vt, Mf, Op, Ls);
    reduce_kernel<<<dim3(4096), 256, 0, stream>>>(Op, Ls, AO);
    oproj_kernel<<<dim3(4, 64), 256, 0, stream>>>(AO, w_out, b_out, out);
}